// Round 8
// baseline (439.941 us; speedup 1.0000x reference)
//
#include <hip/hip_runtime.h>
#include <math.h>

#define BATCH   512
#define IN_DIM  256
#define OUT_DIM 256
#define NDEG    6     // degree+1

#define OT     8     // o per block
#define NSEG   32    // i-segments per block (tid>>3)
#define ISEG   8     // i's per segment
#define NB     8     // b per block (register accumulators)
#define REPEAT 8     // probe amplification factor

// ---------------------------------------------------------------------------
// Real path (R7, unchanged): LSE restructure to polynomials in t=e^x,
// packed (P,Q) Horner via v_pk_fma_f32, pair-batched log2, lane-ordered
// coefficient layout, NB=8 register accumulators, LDS t-staging + reduce.
// R8 adds 5 ablation PROBE kernels after the real path (sink -> workspace)
// to attribute the main kernel's time: full / -log2 / -vmem / -lds / -valu.
// ---------------------------------------------------------------------------

typedef float v2f __attribute__((ext_vector_type(2)));

__device__ __forceinline__ v2f pk_fma(v2f a, v2f b, v2f c) {
    v2f d;
    asm("v_pk_fma_f32 %0, %1, %2, %3" : "=v"(d) : "v"(a), "v"(b), "v"(c));
    return d;
}
__device__ __forceinline__ v2f pk_mul(v2f a, v2f b) {
    v2f d;
    asm("v_pk_mul_f32 %0, %1, %2" : "=v"(d) : "v"(a), "v"(b));
    return d;
}

__global__ void prep_pack(const float* __restrict__ wp,
                          const float* __restrict__ wq,
                          float4* __restrict__ pk2) {
    int j = blockIdx.x * blockDim.x + threadIdx.x;   // j = i*OUT_DIM + o
    if (j >= IN_DIM * OUT_DIM) return;
    const int i = j >> 8, o = j & 255;
    const int seg_blk = i >> 6;
    const int seg     = (i >> 3) & 7;
    const int ii      = i & 7;
    const int o_blk   = o >> 3;
    const int o_l     = o & 7;
    const size_t base =
        ((size_t)(o_blk * 4 + seg_blk) * 24) * 64 + seg * 8 + o_l;

    const float2* wp2 = (const float2*)wp;
    const float2* wq2 = (const float2*)wq;
    float2 p0 = wp2[j * 3], p1 = wp2[j * 3 + 1], p2 = wp2[j * 3 + 2];
    float2 q0 = wq2[j * 3], q1 = wq2[j * 3 + 1], q2 = wq2[j * 3 + 2];
    pk2[base + (ii * 3 + 0) * 64] =
        make_float4(__expf(p0.x), __expf(q0.x), __expf(p0.y), __expf(q0.y));
    pk2[base + (ii * 3 + 1) * 64] =
        make_float4(__expf(p1.x), __expf(q1.x), __expf(p1.y), __expf(q1.y));
    pk2[base + (ii * 3 + 2) * 64] =
        make_float4(__expf(p2.x), __expf(q2.x), __expf(p2.y), __expf(q2.y));
}

#define COMPUTE(iA, a0, a1, a2, e0, e1, e2)                                   \
    {                                                                         \
        const v2f CA0 = {a0.x, a0.y}, CA1 = {a0.z, a0.w};                     \
        const v2f CA2 = {a1.x, a1.y}, CA3 = {a1.z, a1.w};                     \
        const v2f CA4 = {a2.x, a2.y}, CA5 = {a2.z, a2.w};                     \
        const v2f CB0 = {e0.x, e0.y}, CB1 = {e0.z, e0.w};                     \
        const v2f CB2 = {e1.x, e1.y}, CB3 = {e1.z, e1.w};                     \
        const v2f CB4 = {e2.x, e2.y}, CB5 = {e2.z, e2.w};                     \
        _Pragma("unroll")                                                     \
        for (int b = 0; b < NB; ++b) {                                        \
            const float2 tt = *(const float2*)(tb + b * IN_DIM + (iA));       \
            const v2f T0 = {tt.x, tt.x};                                      \
            const v2f T1 = {tt.y, tt.y};                                      \
            v2f PQ0 = pk_fma(CA5, T0, CA4);                                   \
            PQ0 = pk_fma(PQ0, T0, CA3);                                       \
            PQ0 = pk_fma(PQ0, T0, CA2);                                       \
            PQ0 = pk_fma(PQ0, T0, CA1);                                       \
            PQ0 = pk_fma(PQ0, T0, CA0);                                       \
            v2f PQ1 = pk_fma(CB5, T1, CB4);                                   \
            PQ1 = pk_fma(PQ1, T1, CB3);                                       \
            PQ1 = pk_fma(PQ1, T1, CB2);                                       \
            PQ1 = pk_fma(PQ1, T1, CB1);                                       \
            PQ1 = pk_fma(PQ1, T1, CB0);                                       \
            const v2f pr = pk_mul(PQ0, PQ1);                                  \
            acc[b] += __log2f(pr.x) - __log2f(pr.y);                          \
        }                                                                     \
    }

// ---- REAL kernel (R7, unchanged) ----
__launch_bounds__(256, 4)
__global__ void tropical_main(const float* __restrict__ x,
                              const float4* __restrict__ pk2,
                              float* __restrict__ out) {
    __shared__ float lds[NSEG * (NB * OT + 1)];   // 2080 floats

    const int tid = threadIdx.x;
    const int o_l = tid & (OT - 1);
    const int b0  = blockIdx.y * NB;

    {
        const int r = tid >> 5;
        const int c = (tid & 31) * 8;
        const float* xr = x + (size_t)(b0 + r) * IN_DIM + c;
        const float4 v0 = *(const float4*)(xr);
        const float4 v1 = *(const float4*)(xr + 4);
        float4 w0, w1;
        w0.x = __expf(v0.x); w0.y = __expf(v0.y);
        w0.z = __expf(v0.z); w0.w = __expf(v0.w);
        w1.x = __expf(v1.x); w1.y = __expf(v1.y);
        w1.z = __expf(v1.z); w1.w = __expf(v1.w);
        *(float4*)&lds[r * IN_DIM + c]     = w0;
        *(float4*)&lds[r * IN_DIM + c + 4] = w1;
    }
    __syncthreads();

    float acc[NB];
#pragma unroll
    for (int b = 0; b < NB; ++b) acc[b] = 0.f;

    const int lane = tid & 63;
    const int wv   = tid >> 6;
    const float4* __restrict__ cb =
        pk2 + ((size_t)(blockIdx.x * 4 + wv) * 24) * 64 + lane;

    const int i0 = (tid >> 3) * ISEG;
    const float* __restrict__ tb = lds + i0;

    float4 A0 = cb[0 * 64],  A1 = cb[1 * 64],  A2 = cb[2 * 64];
    float4 E0 = cb[3 * 64],  E1 = cb[4 * 64],  E2 = cb[5 * 64];

    float4 B0 = cb[6 * 64],  B1 = cb[7 * 64],  B2 = cb[8 * 64];
    float4 F0 = cb[9 * 64],  F1 = cb[10 * 64], F2 = cb[11 * 64];
    COMPUTE(0, A0, A1, A2, E0, E1, E2);

    A0 = cb[12 * 64]; A1 = cb[13 * 64]; A2 = cb[14 * 64];
    E0 = cb[15 * 64]; E1 = cb[16 * 64]; E2 = cb[17 * 64];
    COMPUTE(2, B0, B1, B2, F0, F1, F2);

    B0 = cb[18 * 64]; B1 = cb[19 * 64]; B2 = cb[20 * 64];
    F0 = cb[21 * 64]; F1 = cb[22 * 64]; F2 = cb[23 * 64];
    COMPUTE(4, A0, A1, A2, E0, E1, E2);

    COMPUTE(6, B0, B1, B2, F0, F1, F2);

    __syncthreads();
    const int seg = tid >> 3;
#pragma unroll
    for (int b = 0; b < NB; ++b)
        lds[seg * (NB * OT + 1) + b * OT + o_l] = acc[b];
    __syncthreads();

    if (tid < NB * OT) {
        const int br = tid >> 3, orr = tid & (OT - 1);
        float s = 0.f;
#pragma unroll
        for (int g = 0; g < NSEG; ++g)
            s += lds[g * (NB * OT + 1) + br * OT + orr];
        out[(size_t)(b0 + br) * OUT_DIM + blockIdx.x * OT + orr] =
            s * 0.6931471805599453f;
    }
}

// ---- ABLATION PROBES (write to workspace sink; REPEAT-amplified) ----
// MODE 0: full   1: no-log2   2: no-vmem (coefs hoisted)
// MODE 3: no-lds (t from formula; staging DCE'd too)   4: valu-lite (5->2 fma)
template<int MODE>
__launch_bounds__(256, 4)
__global__ void probe_main(const float* __restrict__ x,
                           const float4* __restrict__ pk2,
                           float* __restrict__ sink) {
    __shared__ float lds[NSEG * (NB * OT + 1)];
    const int tid = threadIdx.x;
    const int b0  = blockIdx.y * NB;

    {
        const int r = tid >> 5;
        const int c = (tid & 31) * 8;
        const float* xr = x + (size_t)(b0 + r) * IN_DIM + c;
        const float4 v0 = *(const float4*)(xr);
        const float4 v1 = *(const float4*)(xr + 4);
        float4 w0, w1;
        w0.x = __expf(v0.x); w0.y = __expf(v0.y);
        w0.z = __expf(v0.z); w0.w = __expf(v0.w);
        w1.x = __expf(v1.x); w1.y = __expf(v1.y);
        w1.z = __expf(v1.z); w1.w = __expf(v1.w);
        *(float4*)&lds[r * IN_DIM + c]     = w0;
        *(float4*)&lds[r * IN_DIM + c + 4] = w1;
    }
    __syncthreads();

    float acc[NB];
#pragma unroll
    for (int b = 0; b < NB; ++b) acc[b] = 0.f;

    const int lane = tid & 63;
    const int wv   = tid >> 6;
    const float4* __restrict__ cb =
        pk2 + ((size_t)(blockIdx.x * 4 + wv) * 24) * 64 + lane;
    const int i0 = (tid >> 3) * ISEG;
    const float* __restrict__ tb = lds + i0;

    float4 A0, A1, A2, E0, E1, E2;
    if constexpr (MODE == 2) {   // hoist: one coef group for everything
        A0 = cb[0 * 64]; A1 = cb[1 * 64]; A2 = cb[2 * 64];
        E0 = cb[3 * 64]; E1 = cb[4 * 64]; E2 = cb[5 * 64];
    }

#pragma unroll 1
    for (int r = 0; r < REPEAT; ++r) {
        int rz = r;
        asm volatile("" : "+v"(rz));       // opaque copy of r
        const int z = rz - r;              // == 0 at runtime, opaque at compile
        const float4* cbr = cb + z;        // defeats load hoisting across reps
        const float*  tbr = tb + z;        // defeats LDS-read CSE across reps

#pragma unroll
        for (int g = 0; g < 4; ++g) {
            if constexpr (MODE != 2) {
                const float4* cg = cbr + g * 6 * 64;
                A0 = cg[0 * 64]; A1 = cg[1 * 64]; A2 = cg[2 * 64];
                E0 = cg[3 * 64]; E1 = cg[4 * 64]; E2 = cg[5 * 64];
            }
            const int iA = g * 2;
            const v2f CA0 = {A0.x, A0.y}, CA1 = {A0.z, A0.w};
            const v2f CA2 = {A1.x, A1.y}, CA3 = {A1.z, A1.w};
            const v2f CA4 = {A2.x, A2.y}, CA5 = {A2.z, A2.w};
            const v2f CB0 = {E0.x, E0.y}, CB1 = {E0.z, E0.w};
            const v2f CB2 = {E1.x, E1.y}, CB3 = {E1.z, E1.w};
            const v2f CB4 = {E2.x, E2.y}, CB5 = {E2.z, E2.w};
#pragma unroll
            for (int b = 0; b < NB; ++b) {
                float t0, t1;
                if constexpr (MODE == 3) {
                    t0 = 1.0f + 0.001f * (float)(((b << 3) + iA + r) & 31);
                    t1 = t0 + 0.002f;
                } else {
                    const float2 tt = *(const float2*)(tbr + b * IN_DIM + iA);
                    t0 = tt.x; t1 = tt.y;
                }
                const v2f T0 = {t0, t0};
                const v2f T1 = {t1, t1};
                v2f PQ0, PQ1;
                if constexpr (MODE == 4) {     // keep all coef regs live
                    PQ0 = pk_fma(CA5, T0, CA2);
                    PQ0 = pk_fma(PQ0, T0, CA0);
                    PQ1 = pk_fma(CB5, T1, CB2);
                    PQ1 = pk_fma(PQ1, T1, CB0);
                    asm volatile("" :: "v"(CA1), "v"(CA3), "v"(CA4),
                                       "v"(CB1), "v"(CB3), "v"(CB4));
                } else {
                    PQ0 = pk_fma(CA5, T0, CA4);
                    PQ0 = pk_fma(PQ0, T0, CA3);
                    PQ0 = pk_fma(PQ0, T0, CA2);
                    PQ0 = pk_fma(PQ0, T0, CA1);
                    PQ0 = pk_fma(PQ0, T0, CA0);
                    PQ1 = pk_fma(CB5, T1, CB4);
                    PQ1 = pk_fma(PQ1, T1, CB3);
                    PQ1 = pk_fma(PQ1, T1, CB2);
                    PQ1 = pk_fma(PQ1, T1, CB1);
                    PQ1 = pk_fma(PQ1, T1, CB0);
                }
                const v2f pr = pk_mul(PQ0, PQ1);
                if constexpr (MODE == 1) {
                    acc[b] += pr.x - pr.y;     // trans removed, pr stays live
                } else {
                    acc[b] += __log2f(pr.x) - __log2f(pr.y);
                }
            }
        }
    }

    float s = 0.f;
#pragma unroll
    for (int b = 0; b < NB; ++b) s += acc[b];
    sink[((size_t)blockIdx.y * gridDim.x + blockIdx.x) * 256 + tid] = s;
}

// Fallback (workspace too small): direct stabilized LSE.
__global__ void tropical_fallback(const float* __restrict__ x,
                                  const float* __restrict__ wp,
                                  const float* __restrict__ wq,
                                  float* __restrict__ out) {
    const int o = blockIdx.x * 16 + (threadIdx.x & 15);
    const int b = blockIdx.y * 16 + (threadIdx.x >> 4);
    float acc = 0.f;
    for (int i = 0; i < IN_DIM; ++i) {
        const float xv = x[b * IN_DIM + i];
        const float* p = wp + (size_t)(i * OUT_DIM + o) * NDEG;
        const float* q = wq + (size_t)(i * OUT_DIM + o) * NDEG;
        float lp[NDEG], lq[NDEG], mP = -1e30f, mQ = -1e30f;
#pragma unroll
        for (int d = 0; d < NDEG; ++d) {
            lp[d] = xv * d + p[d]; mP = fmaxf(mP, lp[d]);
            lq[d] = xv * d + q[d]; mQ = fmaxf(mQ, lq[d]);
        }
        float sP = 0.f, sQ = 0.f;
#pragma unroll
        for (int d = 0; d < NDEG; ++d) {
            sP += __expf(lp[d] - mP);
            sQ += __expf(lq[d] - mQ);
        }
        acc += (mP + __logf(sP)) - (mQ + __logf(sQ));
    }
    out[b * OUT_DIM + o] = acc;
}

extern "C" void kernel_launch(void* const* d_in, const int* in_sizes, int n_in,
                              void* d_out, int out_size, void* d_ws, size_t ws_size,
                              hipStream_t stream) {
    const float* x  = (const float*)d_in[0];
    const float* wp = (const float*)d_in[2];
    const float* wq = (const float*)d_in[3];
    float* out = (float*)d_out;

    const size_t pk_bytes   = (size_t)IN_DIM * OUT_DIM * 12 * sizeof(float);  // 3 MiB
    const size_t sink_bytes = (size_t)2048 * 256 * sizeof(float);             // 2 MiB

    if (ws_size >= pk_bytes) {
        float4* pk2 = (float4*)d_ws;
        // Sink goes past pk if there's room; else overlap pk (deterministic:
        // prep_pack fully rewrites pk each call, probes run after main).
        float* sink = (ws_size >= pk_bytes + sink_bytes)
                          ? (float*)((char*)d_ws + pk_bytes)
                          : (float*)d_ws;

        prep_pack<<<(IN_DIM * OUT_DIM + 255) / 256, 256, 0, stream>>>(wp, wq, pk2);

        dim3 grid(OUT_DIM / OT, BATCH / NB);   // 32 x 64 = 2048 blocks
        tropical_main<<<grid, 256, 0, stream>>>(x, (const float4*)pk2, out);

        // ---- diagnostic probes (R8 only): per-dispatch durs via rocprof ----
        probe_main<0><<<grid, 256, 0, stream>>>(x, (const float4*)pk2, sink);
        probe_main<1><<<grid, 256, 0, stream>>>(x, (const float4*)pk2, sink);
        probe_main<2><<<grid, 256, 0, stream>>>(x, (const float4*)pk2, sink);
        probe_main<3><<<grid, 256, 0, stream>>>(x, (const float4*)pk2, sink);
        probe_main<4><<<grid, 256, 0, stream>>>(x, (const float4*)pk2, sink);
    } else {
        dim3 grid(OUT_DIM / 16, BATCH / 16);
        tropical_fallback<<<grid, 256, 0, stream>>>(x, wp, wq, out);
    }
}

// Round 9
// 24.226 us; speedup vs baseline: 18.1596x; 18.1596x over previous
//
#include <hip/hip_runtime.h>
#include <math.h>

#define BATCH   512
#define IN_DIM  256
#define OUT_DIM 256
#define NDEG    6     // degree+1

// Geometry (R6/R7-proven): 256 threads = 8 o-lanes x 32 i-segments; NB=8
// b-accumulators per thread. R9: coefficients prescaled by 2^-18 so FOUR
// i-polynomial products fit f32 -> one log2 per 4 triples; t read as b128
// (4 t's); group loads batched (12 float4), no explicit double-buffer.
#define OT     8     // o per block
#define NSEG   32    // i-segments per block (tid>>3)
#define ISEG   8     // i's per segment
#define NB     8     // b per block (register accumulators)

// ---------------------------------------------------------------------------
// LSE_d(x*d + w_d) = log( sum_d e^{w_d} * t^d ),  t = e^x.
// out[b,o] = ln2 * sum_i [ log2 P'_io(t) - log2 Q'_io(t) ]   (2^-18 scale
// cancels exactly between P and Q).  (P,Q) packed dual-f32 Horner via
// v_pk_fma_f32; log2 batched over 4 i's: prod of 4 P' in [2^-74, 2^73].
//
// pk2 layout (R7 lane-ordered, unchanged): slab (o_blk*4 + wv), steps
// k = 0..23 (k = ii*3 + w), each step = 64 contiguous float4 (one per lane).
// ---------------------------------------------------------------------------

typedef float v2f __attribute__((ext_vector_type(2)));

__device__ __forceinline__ v2f pk_fma(v2f a, v2f b, v2f c) {
    v2f d;
    asm("v_pk_fma_f32 %0, %1, %2, %3" : "=v"(d) : "v"(a), "v"(b), "v"(c));
    return d;
}
__device__ __forceinline__ v2f pk_mul(v2f a, v2f b) {
    v2f d;
    asm("v_pk_mul_f32 %0, %1, %2" : "=v"(d) : "v"(a), "v"(b));
    return d;
}

#define PRESCALE 12.476649250079015f   // 18 * ln2

__global__ void prep_pack(const float* __restrict__ wp,
                          const float* __restrict__ wq,
                          float4* __restrict__ pk2) {
    int j = blockIdx.x * blockDim.x + threadIdx.x;   // j = i*OUT_DIM + o
    if (j >= IN_DIM * OUT_DIM) return;
    const int i = j >> 8, o = j & 255;
    const int seg_blk = i >> 6;
    const int seg     = (i >> 3) & 7;
    const int ii      = i & 7;
    const int o_blk   = o >> 3;
    const int o_l     = o & 7;
    const size_t base =
        ((size_t)(o_blk * 4 + seg_blk) * 24) * 64 + seg * 8 + o_l;

    const float2* wp2 = (const float2*)wp;
    const float2* wq2 = (const float2*)wq;
    float2 p0 = wp2[j * 3], p1 = wp2[j * 3 + 1], p2 = wp2[j * 3 + 2];
    float2 q0 = wq2[j * 3], q1 = wq2[j * 3 + 1], q2 = wq2[j * 3 + 2];
    pk2[base + (ii * 3 + 0) * 64] =
        make_float4(__expf(p0.x - PRESCALE), __expf(q0.x - PRESCALE),
                    __expf(p0.y - PRESCALE), __expf(q0.y - PRESCALE));
    pk2[base + (ii * 3 + 1) * 64] =
        make_float4(__expf(p1.x - PRESCALE), __expf(q1.x - PRESCALE),
                    __expf(p1.y - PRESCALE), __expf(q1.y - PRESCALE));
    pk2[base + (ii * 3 + 2) * 64] =
        make_float4(__expf(p2.x - PRESCALE), __expf(q2.x - PRESCALE),
                    __expf(p2.y - PRESCALE), __expf(q2.y - PRESCALE));
}

// Packed Horner for one i: coeff float4s c0=(p0,q0,p1,q1) c1=(p2,q2,p3,q3)
// c2=(p4,q4,p5,q5); T = {t,t}. Returns (P', Q').
__device__ __forceinline__ v2f horner_pq(float4 c0, float4 c1, float4 c2, v2f T) {
    const v2f C0 = {c0.x, c0.y}, C1 = {c0.z, c0.w};
    const v2f C2 = {c1.x, c1.y}, C3 = {c1.z, c1.w};
    const v2f C4 = {c2.x, c2.y}, C5 = {c2.z, c2.w};
    v2f r = pk_fma(C5, T, C4);
    r = pk_fma(r, T, C3);
    r = pk_fma(r, T, C2);
    r = pk_fma(r, T, C1);
    r = pk_fma(r, T, C0);
    return r;
}

// Grid = (OUT_DIM/OT = 32, BATCH/NB = 64) = 2048 blocks = 8/CU.
__launch_bounds__(256, 4)
__global__ void tropical_main(const float* __restrict__ x,
                              const float4* __restrict__ pk2,
                              float* __restrict__ out) {
    // Phase A: t[b][i], 8 b x 256 i (2048 f). Phase B: reduce buffer,
    // NSEG slabs of stride NB*OT+1 = 65 (2080 f). Shared allocation.
    __shared__ float lds[NSEG * (NB * OT + 1)];   // 2080 floats

    const int tid = threadIdx.x;
    const int o_l = tid & (OT - 1);
    const int b0  = blockIdx.y * NB;

    // ---- stage t = exp(x): 8 b-rows x 256 i (8 floats / thread) ----
    {
        const int r = tid >> 5;            // 0..7
        const int c = (tid & 31) * 8;      // 0..248
        const float* xr = x + (size_t)(b0 + r) * IN_DIM + c;
        const float4 v0 = *(const float4*)(xr);
        const float4 v1 = *(const float4*)(xr + 4);
        float4 w0, w1;
        w0.x = __expf(v0.x); w0.y = __expf(v0.y);
        w0.z = __expf(v0.z); w0.w = __expf(v0.w);
        w1.x = __expf(v1.x); w1.y = __expf(v1.y);
        w1.z = __expf(v1.z); w1.w = __expf(v1.w);
        *(float4*)&lds[r * IN_DIM + c]     = w0;
        *(float4*)&lds[r * IN_DIM + c + 4] = w1;
    }
    __syncthreads();

    float acc[NB];
#pragma unroll
    for (int b = 0; b < NB; ++b) acc[b] = 0.f;

    const int lane = tid & 63;
    const int wv   = tid >> 6;
    const float4* __restrict__ cb =
        pk2 + ((size_t)(blockIdx.x * 4 + wv) * 24) * 64 + lane;

    const int i0 = (tid >> 3) * ISEG;
    const float* __restrict__ tb = lds + i0;

#pragma unroll
    for (int g = 0; g < 2; ++g) {          // 2 groups of 4 i's
        // Batched group load: 12 float4 (4 i's x 3 words), lane-contiguous.
        float4 C[12];
#pragma unroll
        for (int k = 0; k < 12; ++k)
            C[k] = cb[(g * 12 + k) * 64];

#pragma unroll
        for (int b = 0; b < NB; ++b) {
            // 4 t's in one ds_read_b128 (2-way bank alias = free).
            const float4 tv = *(const float4*)(tb + b * IN_DIM + g * 4);
            const v2f T0 = {tv.x, tv.x};
            const v2f T1 = {tv.y, tv.y};
            const v2f T2 = {tv.z, tv.z};
            const v2f T3 = {tv.w, tv.w};
            const v2f PQ0 = horner_pq(C[0], C[1],  C[2],  T0);
            const v2f PQ1 = horner_pq(C[3], C[4],  C[5],  T1);
            const v2f PQ2 = horner_pq(C[6], C[7],  C[8],  T2);
            const v2f PQ3 = horner_pq(C[9], C[10], C[11], T3);
            // Product of 4 scaled polys: in [2^-74, 2^73] -> one log2 each.
            const v2f m = pk_mul(pk_mul(PQ0, PQ1), pk_mul(PQ2, PQ3));
            acc[b] += __log2f(m.x) - __log2f(m.y);
        }
    }

    __syncthreads();   // done with t; reuse LDS as reduce buffer
    const int seg = tid >> 3;
#pragma unroll
    for (int b = 0; b < NB; ++b)
        lds[seg * (NB * OT + 1) + b * OT + o_l] = acc[b];
    __syncthreads();

    if (tid < NB * OT) {
        const int br = tid >> 3, orr = tid & (OT - 1);
        float s = 0.f;
#pragma unroll
        for (int g = 0; g < NSEG; ++g)
            s += lds[g * (NB * OT + 1) + br * OT + orr];
        out[(size_t)(b0 + br) * OUT_DIM + blockIdx.x * OT + orr] =
            s * 0.6931471805599453f;   // * ln2
    }
}

// Fallback (workspace too small): direct stabilized LSE.
__global__ void tropical_fallback(const float* __restrict__ x,
                                  const float* __restrict__ wp,
                                  const float* __restrict__ wq,
                                  float* __restrict__ out) {
    const int o = blockIdx.x * 16 + (threadIdx.x & 15);
    const int b = blockIdx.y * 16 + (threadIdx.x >> 4);
    float acc = 0.f;
    for (int i = 0; i < IN_DIM; ++i) {
        const float xv = x[b * IN_DIM + i];
        const float* p = wp + (size_t)(i * OUT_DIM + o) * NDEG;
        const float* q = wq + (size_t)(i * OUT_DIM + o) * NDEG;
        float lp[NDEG], lq[NDEG], mP = -1e30f, mQ = -1e30f;
#pragma unroll
        for (int d = 0; d < NDEG; ++d) {
            lp[d] = xv * d + p[d]; mP = fmaxf(mP, lp[d]);
            lq[d] = xv * d + q[d]; mQ = fmaxf(mQ, lq[d]);
        }
        float sP = 0.f, sQ = 0.f;
#pragma unroll
        for (int d = 0; d < NDEG; ++d) {
            sP += __expf(lp[d] - mP);
            sQ += __expf(lq[d] - mQ);
        }
        acc += (mP + __logf(sP)) - (mQ + __logf(sQ));
    }
    out[b * OUT_DIM + o] = acc;
}

extern "C" void kernel_launch(void* const* d_in, const int* in_sizes, int n_in,
                              void* d_out, int out_size, void* d_ws, size_t ws_size,
                              hipStream_t stream) {
    const float* x  = (const float*)d_in[0];
    // d_in[1] = slopes (arange(6)) — implicit in the polynomial powers.
    const float* wp = (const float*)d_in[2];
    const float* wq = (const float*)d_in[3];
    float* out = (float*)d_out;

    const size_t pk_bytes = (size_t)IN_DIM * OUT_DIM * 12 * sizeof(float);  // 3 MiB

    if (ws_size >= pk_bytes) {
        float4* pk2 = (float4*)d_ws;
        prep_pack<<<(IN_DIM * OUT_DIM + 255) / 256, 256, 0, stream>>>(wp, wq, pk2);

        dim3 grid(OUT_DIM / OT, BATCH / NB);   // 32 x 64 = 2048 blocks
        tropical_main<<<grid, 256, 0, stream>>>(x, (const float4*)pk2, out);
    } else {
        dim3 grid(OUT_DIM / 16, BATCH / 16);
        tropical_fallback<<<grid, 256, 0, stream>>>(x, wp, wq, out);
    }
}

// Round 10
// 23.297 us; speedup vs baseline: 18.8837x; 1.0399x over previous
//
#include <hip/hip_runtime.h>
#include <math.h>

#define BATCH   512
#define IN_DIM  256
#define OUT_DIM 256
#define NDEG    6     // degree+1

// Geometry (R6/R7-proven): 256 threads = 8 o-lanes x 32 i-segments; NB=8
// b-accumulators per thread; lane-ordered coef layout; 2^-18 prescale so a
// product of 4 scaled polys fits f32 -> one log2 per 4 triples.
// R10: v_pk_fma_f32 op_sel BROADCAST of t from the float4 sub-pairs --
// removes all 8 v_mov per (group,b) that R4-R9 spent forming {t,t} pairs.
#define OT     8     // o per block
#define NSEG   32    // i-segments per block (tid>>3)
#define ISEG   8     // i's per segment
#define NB     8     // b per block (register accumulators)

typedef float v2f __attribute__((ext_vector_type(2)));

// d = a * broadcast(lo32(t)) + c   (op_sel_hi[1]=0 -> hi result uses lo src)
__device__ __forceinline__ v2f pk_fma_blo(v2f a, v2f t, v2f c) {
    v2f d;
    asm("v_pk_fma_f32 %0, %1, %2, %3 op_sel:[0,0,0] op_sel_hi:[1,0,1]"
        : "=v"(d) : "v"(a), "v"(t), "v"(c));
    return d;
}
// d = a * broadcast(hi32(t)) + c   (op_sel[1]=1, op_sel_hi[1]=1)
__device__ __forceinline__ v2f pk_fma_bhi(v2f a, v2f t, v2f c) {
    v2f d;
    asm("v_pk_fma_f32 %0, %1, %2, %3 op_sel:[0,1,0] op_sel_hi:[1,1,1]"
        : "=v"(d) : "v"(a), "v"(t), "v"(c));
    return d;
}
__device__ __forceinline__ v2f pk_mul(v2f a, v2f b) {
    v2f d;
    asm("v_pk_mul_f32 %0, %1, %2" : "=v"(d) : "v"(a), "v"(b));
    return d;
}

#define PRESCALE 12.476649250079015f   // 18 * ln2

// pk2 layout (R7 lane-ordered): slab (o_blk*4 + wv), steps k = ii*3 + w,
// each step = 64 contiguous float4 (one per lane).
// float4 word w: (p_{2w}, q_{2w}, p_{2w+1}, q_{2w+1}), coefs = exp(w - 18ln2).
__global__ void prep_pack(const float* __restrict__ wp,
                          const float* __restrict__ wq,
                          float4* __restrict__ pk2) {
    int j = blockIdx.x * blockDim.x + threadIdx.x;   // j = i*OUT_DIM + o
    if (j >= IN_DIM * OUT_DIM) return;
    const int i = j >> 8, o = j & 255;
    const int seg_blk = i >> 6;
    const int seg     = (i >> 3) & 7;
    const int ii      = i & 7;
    const int o_blk   = o >> 3;
    const int o_l     = o & 7;
    const size_t base =
        ((size_t)(o_blk * 4 + seg_blk) * 24) * 64 + seg * 8 + o_l;

    const float2* wp2 = (const float2*)wp;
    const float2* wq2 = (const float2*)wq;
    float2 p0 = wp2[j * 3], p1 = wp2[j * 3 + 1], p2 = wp2[j * 3 + 2];
    float2 q0 = wq2[j * 3], q1 = wq2[j * 3 + 1], q2 = wq2[j * 3 + 2];
    pk2[base + (ii * 3 + 0) * 64] =
        make_float4(__expf(p0.x - PRESCALE), __expf(q0.x - PRESCALE),
                    __expf(p0.y - PRESCALE), __expf(q0.y - PRESCALE));
    pk2[base + (ii * 3 + 1) * 64] =
        make_float4(__expf(p1.x - PRESCALE), __expf(q1.x - PRESCALE),
                    __expf(p1.y - PRESCALE), __expf(q1.y - PRESCALE));
    pk2[base + (ii * 3 + 2) * 64] =
        make_float4(__expf(p2.x - PRESCALE), __expf(q2.x - PRESCALE),
                    __expf(p2.y - PRESCALE), __expf(q2.y - PRESCALE));
}

// Packed Horner, t broadcast straight from a (t0,t1) register pair via op_sel.
__device__ __forceinline__ v2f horner_lo(float4 c0, float4 c1, float4 c2, v2f tp) {
    const v2f C0 = {c0.x, c0.y}, C1 = {c0.z, c0.w};
    const v2f C2 = {c1.x, c1.y}, C3 = {c1.z, c1.w};
    const v2f C4 = {c2.x, c2.y}, C5 = {c2.z, c2.w};
    v2f r = pk_fma_blo(C5, tp, C4);
    r = pk_fma_blo(r, tp, C3);
    r = pk_fma_blo(r, tp, C2);
    r = pk_fma_blo(r, tp, C1);
    r = pk_fma_blo(r, tp, C0);
    return r;
}
__device__ __forceinline__ v2f horner_hi(float4 c0, float4 c1, float4 c2, v2f tp) {
    const v2f C0 = {c0.x, c0.y}, C1 = {c0.z, c0.w};
    const v2f C2 = {c1.x, c1.y}, C3 = {c1.z, c1.w};
    const v2f C4 = {c2.x, c2.y}, C5 = {c2.z, c2.w};
    v2f r = pk_fma_bhi(C5, tp, C4);
    r = pk_fma_bhi(r, tp, C3);
    r = pk_fma_bhi(r, tp, C2);
    r = pk_fma_bhi(r, tp, C1);
    r = pk_fma_bhi(r, tp, C0);
    return r;
}

// Grid = (OUT_DIM/OT = 32, BATCH/NB = 64) = 2048 blocks = 8/CU.
__launch_bounds__(256, 4)
__global__ void tropical_main(const float* __restrict__ x,
                              const float4* __restrict__ pk2,
                              float* __restrict__ out) {
    // Phase A: t[b][i], 8 b x 256 i (2048 f). Phase B: reduce buffer,
    // NSEG slabs of stride NB*OT+1 = 65 (2080 f). Shared allocation.
    __shared__ float lds[NSEG * (NB * OT + 1)];   // 2080 floats

    const int tid = threadIdx.x;
    const int o_l = tid & (OT - 1);
    const int b0  = blockIdx.y * NB;

    // ---- stage t = exp(x): 8 b-rows x 256 i (8 floats / thread) ----
    {
        const int r = tid >> 5;            // 0..7
        const int c = (tid & 31) * 8;      // 0..248
        const float* xr = x + (size_t)(b0 + r) * IN_DIM + c;
        const float4 v0 = *(const float4*)(xr);
        const float4 v1 = *(const float4*)(xr + 4);
        float4 w0, w1;
        w0.x = __expf(v0.x); w0.y = __expf(v0.y);
        w0.z = __expf(v0.z); w0.w = __expf(v0.w);
        w1.x = __expf(v1.x); w1.y = __expf(v1.y);
        w1.z = __expf(v1.z); w1.w = __expf(v1.w);
        *(float4*)&lds[r * IN_DIM + c]     = w0;
        *(float4*)&lds[r * IN_DIM + c + 4] = w1;
    }
    __syncthreads();

    float acc[NB];
#pragma unroll
    for (int b = 0; b < NB; ++b) acc[b] = 0.f;

    const int lane = tid & 63;
    const int wv   = tid >> 6;
    const float4* __restrict__ cb =
        pk2 + ((size_t)(blockIdx.x * 4 + wv) * 24) * 64 + lane;

    const int i0 = (tid >> 3) * ISEG;
    const float* __restrict__ tb = lds + i0;

#pragma unroll
    for (int g = 0; g < 2; ++g) {          // 2 groups of 4 i's
        // Batched group load: 12 float4 (4 i's x 3 words), lane-contiguous.
        float4 C[12];
#pragma unroll
        for (int k = 0; k < 12; ++k)
            C[k] = cb[(g * 12 + k) * 64];

#pragma unroll
        for (int b = 0; b < NB; ++b) {
            // 4 t's in one ds_read_b128; sub-pairs feed op_sel broadcast.
            const float4 tv = *(const float4*)(tb + b * IN_DIM + g * 4);
            const v2f txy = {tv.x, tv.y};   // same VGPR pair, no mov
            const v2f tzw = {tv.z, tv.w};
            const v2f PQ0 = horner_lo(C[0], C[1],  C[2],  txy);  // t = tv.x
            const v2f PQ1 = horner_hi(C[3], C[4],  C[5],  txy);  // t = tv.y
            const v2f PQ2 = horner_lo(C[6], C[7],  C[8],  tzw);  // t = tv.z
            const v2f PQ3 = horner_hi(C[9], C[10], C[11], tzw);  // t = tv.w
            // Product of 4 scaled polys: in [2^-74, 2^73] -> one log2 each.
            const v2f m = pk_mul(pk_mul(PQ0, PQ1), pk_mul(PQ2, PQ3));
            acc[b] += __log2f(m.x) - __log2f(m.y);
        }
    }

    __syncthreads();   // done with t; reuse LDS as reduce buffer
    const int seg = tid >> 3;
#pragma unroll
    for (int b = 0; b < NB; ++b)
        lds[seg * (NB * OT + 1) + b * OT + o_l] = acc[b];
    __syncthreads();

    if (tid < NB * OT) {
        const int br = tid >> 3, orr = tid & (OT - 1);
        float s = 0.f;
#pragma unroll
        for (int g = 0; g < NSEG; ++g)
            s += lds[g * (NB * OT + 1) + br * OT + orr];
        out[(size_t)(b0 + br) * OUT_DIM + blockIdx.x * OT + orr] =
            s * 0.6931471805599453f;   // * ln2
    }
}

// Fallback (workspace too small): direct stabilized LSE.
__global__ void tropical_fallback(const float* __restrict__ x,
                                  const float* __restrict__ wp,
                                  const float* __restrict__ wq,
                                  float* __restrict__ out) {
    const int o = blockIdx.x * 16 + (threadIdx.x & 15);
    const int b = blockIdx.y * 16 + (threadIdx.x >> 4);
    float acc = 0.f;
    for (int i = 0; i < IN_DIM; ++i) {
        const float xv = x[b * IN_DIM + i];
        const float* p = wp + (size_t)(i * OUT_DIM + o) * NDEG;
        const float* q = wq + (size_t)(i * OUT_DIM + o) * NDEG;
        float lp[NDEG], lq[NDEG], mP = -1e30f, mQ = -1e30f;
#pragma unroll
        for (int d = 0; d < NDEG; ++d) {
            lp[d] = xv * d + p[d]; mP = fmaxf(mP, lp[d]);
            lq[d] = xv * d + q[d]; mQ = fmaxf(mQ, lq[d]);
        }
        float sP = 0.f, sQ = 0.f;
#pragma unroll
        for (int d = 0; d < NDEG; ++d) {
            sP += __expf(lp[d] - mP);
            sQ += __expf(lq[d] - mQ);
        }
        acc += (mP + __logf(sP)) - (mQ + __logf(sQ));
    }
    out[b * OUT_DIM + o] = acc;
}

extern "C" void kernel_launch(void* const* d_in, const int* in_sizes, int n_in,
                              void* d_out, int out_size, void* d_ws, size_t ws_size,
                              hipStream_t stream) {
    const float* x  = (const float*)d_in[0];
    // d_in[1] = slopes (arange(6)) — implicit in the polynomial powers.
    const float* wp = (const float*)d_in[2];
    const float* wq = (const float*)d_in[3];
    float* out = (float*)d_out;

    const size_t pk_bytes = (size_t)IN_DIM * OUT_DIM * 12 * sizeof(float);  // 3 MiB

    if (ws_size >= pk_bytes) {
        float4* pk2 = (float4*)d_ws;
        prep_pack<<<(IN_DIM * OUT_DIM + 255) / 256, 256, 0, stream>>>(wp, wq, pk2);

        dim3 grid(OUT_DIM / OT, BATCH / NB);   // 32 x 64 = 2048 blocks
        tropical_main<<<grid, 256, 0, stream>>>(x, (const float4*)pk2, out);
    } else {
        dim3 grid(OUT_DIM / 16, BATCH / 16);
        tropical_fallback<<<grid, 256, 0, stream>>>(x, wp, wq, out);
    }
}